// Round 6
// baseline (520.827 us; speedup 1.0000x reference)
//
#include <hip/hip_runtime.h>

#define B_ 8192
#define D_ 2048

typedef unsigned int u32;
typedef __attribute__((ext_vector_type(8)))  short bf16x8;
typedef __attribute__((ext_vector_type(16))) float f32x16;

__device__ __forceinline__ float dot4(float4 a, float4 b) {
  return a.x*b.x + a.y*b.y + a.z*b.z + a.w*b.w;
}

// fp32 -> bf16 hi/lo truncation split (v = hi + lo, exact to 16 mantissa bits).
__device__ __forceinline__ void split2(float a, float b, u32& h, u32& l) {
  u32 ua = __float_as_uint(a), ub = __float_as_uint(b);
  h = __builtin_amdgcn_perm(ub, ua, 0x07060302u);
  float la = a - __uint_as_float(ua & 0xFFFF0000u);
  float lb = b - __uint_as_float(ub & 0xFFFF0000u);
  l = __builtin_amdgcn_perm(__float_as_uint(lb), __float_as_uint(la), 0x07060302u);
}
__device__ __forceinline__ void split8(float4 f0, float4 f1, uint4& hi, uint4& lo) {
  split2(f0.x, f0.y, hi.x, lo.x);
  split2(f0.z, f0.w, hi.y, lo.y);
  split2(f1.x, f1.y, hi.z, lo.z);
  split2(f1.z, f1.w, hi.w, lo.w);
}

__device__ __forceinline__ f32x16 mfma32(uint4 a, uint4 b, f32x16 c) {
  return __builtin_amdgcn_mfma_f32_32x32x16_bf16(
      __builtin_bit_cast(bf16x8, a), __builtin_bit_cast(bf16x8, b), c, 0, 0, 0);
}

__global__ void k_zero(int* __restrict__ counts) {
  if (threadIdx.x < 16) counts[threadIdx.x] = 0;
}

// ============ parent (exact fp32) + fused parent_proj ============
// 512 blocks x 512 threads; 16 rows/block, 2 rows/wave; 2 blocks/CU.
__global__ __launch_bounds__(512, 4) void k_parent(
    const float* __restrict__ x, const float* __restrict__ wfc,
    const float* __restrict__ bfc, const float* __restrict__ wp,
    const float* __restrict__ bp, float* __restrict__ out_pl,
    float* __restrict__ out_pp, int* __restrict__ cls, int* __restrict__ counts)
{
  __shared__ float wl[16 * 512];
  __shared__ float pl_lds[16][20];
  const int tid  = threadIdx.x;
  const int wave = tid >> 6, lane = tid & 63;
  const int row0 = blockIdx.x * 16 + wave * 2;

  // pproj weights: thread owns wp rows p0, p0+1 (32 f32 in regs)
  const int p0 = tid * 2;
  float4 wq[8];
  #pragma unroll
  for (int q = 0; q < 8; ++q) wq[q] = ((const float4*)(wp + p0 * 16))[q];
  const float bq0 = bp[p0], bq1 = bp[p0 + 1];

  float acc[2][16];
  #pragma unroll
  for (int r = 0; r < 2; ++r)
    #pragma unroll
    for (int e = 0; e < 16; ++e) acc[r][e] = 0.f;

  for (int ch = 0; ch < 4; ++ch) {            // 4 chunks of 512 over D
    __syncthreads();
    #pragma unroll
    for (int it = 0; it < 4; ++it) {
      int i = tid * 4 + it * 2048;
      int e = i >> 9, k = i & 511;
      *(float4*)&wl[i] = *(const float4*)&wfc[e * 2048 + ch * 512 + k];
    }
    __syncthreads();
    float4 xv[2][2];
    #pragma unroll
    for (int r = 0; r < 2; ++r) {
      const float* xr = x + (size_t)(row0 + r) * D_ + ch * 512;
      xv[r][0] = *(const float4*)&xr[lane * 4];
      xv[r][1] = *(const float4*)&xr[lane * 4 + 256];
    }
    #pragma unroll
    for (int e = 0; e < 16; ++e) {
      float4 w0 = *(const float4*)&wl[e * 512 + lane * 4];
      float4 w1 = *(const float4*)&wl[e * 512 + lane * 4 + 256];
      #pragma unroll
      for (int r = 0; r < 2; ++r)
        acc[r][e] += dot4(xv[r][0], w0) + dot4(xv[r][1], w1);
    }
  }
  #pragma unroll
  for (int r = 0; r < 2; ++r)
    #pragma unroll
    for (int e = 0; e < 16; ++e) {
      float v = acc[r][e];
      #pragma unroll
      for (int m = 32; m >= 1; m >>= 1) v += __shfl_xor(v, m, 64);
      acc[r][e] = v;
    }
  if (lane < 2) {
    const int r = lane;
    const int row = row0 + r;
    float z[16]; float s = 0.f;
    #pragma unroll
    for (int e = 0; e < 16; ++e) { z[e] = acc[r][e] + bfc[e]; s += z[e]; }
    const float mu = s * (1.f / 16.f);
    float s2 = 0.f;
    #pragma unroll
    for (int e = 0; e < 16; ++e) { float d = z[e] - mu; s2 += d * d; }
    const float rstd = rsqrtf(s2 * (1.f / 16.f) + 1e-5f);
    int best = 0; float bv = z[0];
    #pragma unroll
    for (int e = 1; e < 16; ++e) if (z[e] > bv) { bv = z[e]; best = e; }
    #pragma unroll
    for (int e = 0; e < 16; ++e) {
      const float zn = (z[e] - mu) * rstd;
      out_pl[(size_t)row * 16 + e] = zn;
      pl_lds[wave * 2 + r][e] = zn;
    }
    cls[row] = best;
    atomicAdd(&counts[best], 1);
  }
  __syncthreads();
  // pproj: out_pp[row][p] = dot16(pl[row], wp[p]) + bp[p]
  #pragma unroll 4
  for (int r = 0; r < 16; ++r) {
    float4 a0 = *(const float4*)&pl_lds[r][0];
    float4 a1 = *(const float4*)&pl_lds[r][4];
    float4 a2 = *(const float4*)&pl_lds[r][8];
    float4 a3 = *(const float4*)&pl_lds[r][12];
    float o0 = dot4(a0, wq[0]) + dot4(a1, wq[1]) + dot4(a2, wq[2]) + dot4(a3, wq[3]) + bq0;
    float o1 = dot4(a0, wq[4]) + dot4(a1, wq[5]) + dot4(a2, wq[6]) + dot4(a3, wq[7]) + bq1;
    float2 ov = {o0, o1};
    *(float2*)&out_pp[(size_t)(blockIdx.x * 16 + r) * 1024 + p0] = ov;
  }
}

__global__ void k_scan(const int* __restrict__ counts,
                       int* __restrict__ starts, int* __restrict__ cursor) {
  if (threadIdx.x == 0) {
    int run = 0;
    for (int e = 0; e < 16; ++e) { starts[e] = run; cursor[e] = run; run += counts[e]; }
  }
}

__global__ __launch_bounds__(256) void k_scatter(
    const int* __restrict__ cls, int* __restrict__ cursor, int* __restrict__ idxb) {
  const int b = blockIdx.x * 256 + threadIdx.x;
  const int c = cls[b];
  const int pos = atomicAdd(&cursor[c], 1);
  idxb[pos] = b;
}

// ============ fused child level: 32-row tiles, 8 waves, split-bf16 MFMA ============
// wave = (ng = wave%NG picks 32-col frag, kq = wave/NG picks K-segment).
// frag maps (m74/m101): A row=l&31,k=(l>>5)*8+i ; B col=l&31 ; C/D col=l&31,
// row=(r&3)+8*(r>>2)+4*(l>>5).
// LDS: red (K-split partials, 17-dword lane stride = conflict-free) then
//      hbuf[32][C+4] f32 (aliased, consumed-before-overwrite), + snm + rid.
template<int C>
__device__ __forceinline__ void child_body(
    float* smemf, int* rid_s, float* snm,
    const float* __restrict__ x, const float* __restrict__ wfc,
    const float* __restrict__ bfc, const float* __restrict__ wpj,
    const float* __restrict__ bpj, const int* __restrict__ starts,
    const int* __restrict__ counts, const int* __restrict__ idxb,
    float* __restrict__ out_cl, float* __restrict__ out_cp,
    const int e, const int t)
{
  constexpr int NG = C / 32;          // n-frag groups
  constexpr int KSPL = 8 / NG;        // K-split factor (4 | 2)
  constexpr int KSTEPS = 128 / KSPL;  // K16 steps per wave
  constexpr int KS = C / 16;          // proj K16 steps
  const int tid = threadIdx.x;
  const int lane = tid & 63, wave = tid >> 6;
  const int l31 = lane & 31, lh = lane >> 5;
  const int ng = wave % NG, kq = wave / NG;

  const int n = counts[e];
  const int r0 = t * 32;
  if (r0 >= n) return;                 // uniform early-exit (before any barrier)
  const int rows = min(32, n - r0);
  if (tid < 32) rid_s[tid] = idxb[starts[e] + r0 + min(tid, rows - 1)];
  __syncthreads();

  // ---------------- fc: z[32][C] = X[32][2048] @ Wfc[C][2048]^T ----------------
  const float* xa = x + (size_t)rid_s[l31] * D_ + lh * 8;
  const float* wa = wfc + (size_t)(e * C + ng * 32 + l31) * D_ + lh * 8;
  const int kbase = kq * (KSTEPS * 16);

  f32x16 acc;
  #pragma unroll
  for (int r = 0; r < 16; ++r) acc[r] = 0.f;

  float4 a0 = *(const float4*)(xa + kbase);
  float4 a1 = *(const float4*)(xa + kbase + 4);
  float4 b0 = *(const float4*)(wa + kbase);
  float4 b1 = *(const float4*)(wa + kbase + 4);
  for (int s = 0; s < KSTEPS; ++s) {
    float4 na0, na1, nb0, nb1;
    if (s + 1 < KSTEPS) {               // prefetch next K16 before MFMA chain
      const int kn = kbase + (s + 1) * 16;
      na0 = *(const float4*)(xa + kn);
      na1 = *(const float4*)(xa + kn + 4);
      nb0 = *(const float4*)(wa + kn);
      nb1 = *(const float4*)(wa + kn + 4);
    }
    uint4 xh, xl, wh, wl2;
    split8(a0, a1, xh, xl);
    split8(b0, b1, wh, wl2);
    acc = mfma32(xh, wh,  acc);
    acc = mfma32(xh, wl2, acc);
    acc = mfma32(xl, wh,  acc);
    a0 = na0; a1 = na1; b0 = nb0; b1 = nb1;
  }

  // ---------------- K-split reduce via LDS (lane stride 17 dwords) ----------------
  __syncthreads();
  if (kq > 0) {
    float* p = smemf + ((ng * (KSPL - 1) + (kq - 1)) * 64 + lane) * 17;
    #pragma unroll
    for (int r = 0; r < 16; ++r) p[r] = acc[r];
  }
  __syncthreads();

  float h[16];
  if (kq == 0) {
    #pragma unroll
    for (int sl = 0; sl < KSPL - 1; ++sl) {
      const float* p = smemf + ((ng * (KSPL - 1) + sl) * 64 + lane) * 17;
      #pragma unroll
      for (int r = 0; r < 16; ++r) acc[r] += p[r];
    }
    const float bias = bfc[e * C + ng * 32 + l31];
    #pragma unroll
    for (int r = 0; r < 16; ++r) h[r] = acc[r] + bias;
    // LN partials: per reg r, sum over this wave's 32 cols (l31 lanes)
    #pragma unroll
    for (int r = 0; r < 16; ++r) {
      float sv = h[r], qv = h[r] * h[r];
      #pragma unroll
      for (int m = 1; m < 32; m <<= 1) { sv += __shfl_xor(sv, m, 64); qv += __shfl_xor(qv, m, 64); }
      if (l31 == 0) {
        const int row = (r & 3) + 8 * (r >> 2) + 4 * lh;
        snm[(ng * 32 + row) * 2 + 0] = sv;
        snm[(ng * 32 + row) * 2 + 1] = qv;
      }
    }
  }
  __syncthreads();

  float* hbuf = smemf;                 // alias over red region (fully consumed)
  if (kq == 0) {
    #pragma unroll
    for (int r = 0; r < 16; ++r) {
      const int row = (r & 3) + 8 * (r >> 2) + 4 * lh;
      float S = 0.f, Q = 0.f;
      #pragma unroll
      for (int g = 0; g < NG; ++g) {
        S += snm[(g * 32 + row) * 2 + 0];
        Q += snm[(g * 32 + row) * 2 + 1];
      }
      const float mu = S * (1.f / C);
      const float var = Q * (1.f / C) - mu * mu;
      const float rstd = rsqrtf(var + 1e-5f);
      const float hn = (h[r] - mu) * rstd;
      const int col = ng * 32 + l31;
      if (row < rows) out_cl[(size_t)rid_s[row] * C + col] = hn;
      hbuf[row * (C + 4) + col] = hn;
    }
  }
  __syncthreads();

  // ---------------- proj A-frags from hbuf (all waves, own regs) ----------------
  uint4 pah[KS], pal[KS];
  #pragma unroll
  for (int ks = 0; ks < KS; ++ks) {
    const float* hp = hbuf + l31 * (C + 4) + ks * 16 + lh * 8;
    split8(*(const float4*)hp, *(const float4*)(hp + 4), pah[ks], pal[ks]);
  }

  // ---------------- proj: out_cp[32][1024] = h[32][C] @ Wp[1024][C]^T ----------
  for (int j = 0; j < 4; ++j) {
    const int p32 = j * 8 + wave;
    const float* wb = wpj + (size_t)(e * 1024 + p32 * 32 + l31) * C + lh * 8;
    f32x16 p;
    #pragma unroll
    for (int r = 0; r < 16; ++r) p[r] = 0.f;
    #pragma unroll
    for (int ks = 0; ks < KS; ++ks) {
      float4 f0 = *(const float4*)(wb + ks * 16);
      float4 f1 = *(const float4*)(wb + ks * 16 + 4);
      uint4 wh, wl2;
      split8(f0, f1, wh, wl2);
      p = mfma32(pah[ks], wh,  p);
      p = mfma32(pah[ks], wl2, p);
      p = mfma32(pal[ks], wh,  p);
    }
    const float bias = bpj[e * 1024 + p32 * 32 + l31];
    #pragma unroll
    for (int r = 0; r < 16; ++r) {
      const int row = (r & 3) + 8 * (r >> 2) + 4 * lh;
      if (row < rows)
        out_cp[(size_t)rid_s[row] * 1024 + p32 * 32 + l31] = p[r] + bias;
    }
  }
}

// merged launch: both child levels; e in low 4 bits => expert/XCD L2 affinity.
// grid = 16 e x 2 lvl x 256 t = 8192 blocks (non-working blocks exit fast).
__global__ __launch_bounds__(512, 4) void k_child_both(
    const float* __restrict__ x,
    const float* __restrict__ wfc0, const float* __restrict__ bfc0,
    const float* __restrict__ wpj0, const float* __restrict__ bpj0,
    const float* __restrict__ wfc1, const float* __restrict__ bfc1,
    const float* __restrict__ wpj1, const float* __restrict__ bpj1,
    const int* __restrict__ starts, const int* __restrict__ counts,
    const int* __restrict__ idxb,
    float* __restrict__ out_cl0, float* __restrict__ out_cp0,
    float* __restrict__ out_cl1, float* __restrict__ out_cp1)
{
  __shared__ __align__(16) float smemf[6528];   // 26112 B: red region / hbuf alias
  __shared__ int rid_s[32];
  __shared__ float snm[4 * 32 * 2];
  const int e = blockIdx.x & 15;
  const int lvl = (blockIdx.x >> 4) & 1;
  const int t = blockIdx.x >> 5;
  if (lvl == 0)
    child_body<64>(smemf, rid_s, snm, x, wfc0, bfc0, wpj0, bpj0,
                   starts, counts, idxb, out_cl0, out_cp0, e, t);
  else
    child_body<128>(smemf, rid_s, snm, x, wfc1, bfc1, wpj1, bpj1,
                    starts, counts, idxb, out_cl1, out_cp1, e, t);
}

extern "C" void kernel_launch(void* const* d_in, const int* in_sizes, int n_in,
                              void* d_out, int out_size, void* d_ws, size_t ws_size,
                              hipStream_t stream)
{
  (void)in_sizes; (void)n_in; (void)out_size; (void)ws_size;
  const float* x       = (const float*)d_in[0];
  const float* pw_fc   = (const float*)d_in[1];
  const float* pb_fc   = (const float*)d_in[2];
  const float* pw_proj = (const float*)d_in[3];
  const float* pb_proj = (const float*)d_in[4];
  const float* cw_fc0  = (const float*)d_in[5];
  const float* cb_fc0  = (const float*)d_in[6];
  const float* cw_pj0  = (const float*)d_in[7];
  const float* cb_pj0  = (const float*)d_in[8];
  const float* cw_fc1  = (const float*)d_in[9];
  const float* cb_fc1  = (const float*)d_in[10];
  const float* cw_pj1  = (const float*)d_in[11];
  const float* cb_pj1  = (const float*)d_in[12];

  float* out = (float*)d_out;
  float* out_pl  = out;                                   // [B,16]
  float* out_cl0 = out_pl  + (size_t)B_ * 16;             // [B,64]
  float* out_cl1 = out_cl0 + (size_t)B_ * 64;             // [B,128]
  float* out_pp  = out_cl1 + (size_t)B_ * 128;            // [B,1024]
  float* out_cp0 = out_pp  + (size_t)B_ * 1024;           // [B,1024]
  float* out_cp1 = out_cp0 + (size_t)B_ * 1024;           // [B,1024]

  int* cls    = (int*)d_ws;       // [B]
  int* idxb   = cls + B_;         // [B]
  int* counts = idxb + B_;        // [16]
  int* starts = counts + 16;      // [16]
  int* cursor = starts + 16;      // [16]

  k_zero<<<1, 64, 0, stream>>>(counts);
  k_parent<<<512, 512, 0, stream>>>(x, pw_fc, pb_fc, pw_proj, pb_proj,
                                    out_pl, out_pp, cls, counts);
  k_scan<<<1, 64, 0, stream>>>(counts, starts, cursor);
  k_scatter<<<B_ / 256, 256, 0, stream>>>(cls, cursor, idxb);
  k_child_both<<<8192, 512, 0, stream>>>(
      x, cw_fc0, cb_fc0, cw_pj0, cb_pj0, cw_fc1, cb_fc1, cw_pj1, cb_pj1,
      starts, counts, idxb, out_cl0, out_cp0, out_cl1, out_cp1);
}